// Round 15
// baseline (714.219 us; speedup 1.0000x reference)
//
#include <hip/hip_runtime.h>
#include <math.h>

#define NN 100000
#define EE 400000
#define DD 128
#define PB 256    // persistent proj blocks (1/CU)
#define PBH 128   // per node type

typedef __attribute__((ext_vector_type(8))) short bf16x8;
typedef __attribute__((ext_vector_type(4))) float f32x4;

#if defined(__has_builtin)
#if __has_builtin(__builtin_amdgcn_fdot2_f32_bf16)
#define HAVE_FDOT2 1
typedef __attribute__((ext_vector_type(2))) __bf16 bf16x2t;
#endif
#endif

__device__ __forceinline__ unsigned short f2bf(float f) {
  unsigned u = __float_as_uint(f);
  u += 0x7FFF + ((u >> 16) & 1);   // round-to-nearest-even
  return (unsigned short)(u >> 16);
}
__device__ __forceinline__ float bf2f(unsigned short u) {
  return __uint_as_float(((unsigned)u) << 16);
}

// ---- one-shot weight prep (+ deg zeroing appended as extra blocks)
__global__ __launch_bounds__(256) void prep_weights(
    const float* __restrict__ Wp_dr, const float* __restrict__ bp_dr,
    const float* __restrict__ Wp_di, const float* __restrict__ bp_di,
    const float* __restrict__ Wu_dr, const float* __restrict__ Wu_di,
    const float* __restrict__ Bk0, const float* __restrict__ Bv0,
    const float* __restrict__ Bk1, const float* __restrict__ Bv1,
    unsigned short* __restrict__ Wpt_dr, unsigned short* __restrict__ Wpt_di,
    unsigned short* __restrict__ Wut_dr, unsigned short* __restrict__ Wut_di,
    unsigned short* __restrict__ Wkt0, float* __restrict__ bk0,
    unsigned short* __restrict__ Wvt0, float* __restrict__ bv0,
    unsigned short* __restrict__ Wkt1, float* __restrict__ bk1,
    unsigned short* __restrict__ Wvt1, float* __restrict__ bv1,
    int* __restrict__ deg) {
  const int b = blockIdx.x, t = threadIdx.x;
  if (b < 256) {
    const int id = b * 256 + t;
    const int m = id >> 14, rem = id & 16383, k = rem & 127, c = rem >> 7;
    const float* W = (m == 0) ? Wp_dr : (m == 1) ? Wp_di : (m == 2) ? Wu_dr : Wu_di;
    unsigned short* O = (m == 0) ? Wpt_dr : (m == 1) ? Wpt_di : (m == 2) ? Wut_dr : Wut_di;
    O[c * DD + k] = f2bf(W[(size_t)k * DD + c]);
  } else if (b < 512) {
    const int id = (b - 256) * 256 + t;
    const int m = id >> 14, rem = id & 16383, k = rem & 127, c = rem >> 7;
    const float* A = (m < 2) ? Wp_dr : Wp_di;
    const float* B = (m == 0) ? Bk0 : (m == 1) ? Bv0 : (m == 2) ? Bk1 : Bv1;
    unsigned short* O = (m == 0) ? Wkt0 : (m == 1) ? Wvt0 : (m == 2) ? Wkt1 : Wvt1;
    const float4* a4 = (const float4*)(A + (size_t)k * DD);
    float s = 0.0f;
#pragma unroll 8
    for (int j4 = 0; j4 < 32; ++j4) {
      const float4 av = a4[j4];
      s += av.x * B[(4 * j4 + 0) * DD + c] + av.y * B[(4 * j4 + 1) * DD + c]
         + av.z * B[(4 * j4 + 2) * DD + c] + av.w * B[(4 * j4 + 3) * DD + c];
    }
    O[c * DD + k] = f2bf(s);
  } else if (b < 514) {
    const int id = (b - 512) * 256 + t;
    if (id < 512) {
      const int m = id >> 7, c = id & 127;
      const float* bp = (m < 2) ? bp_dr : bp_di;
      const float* B = (m == 0) ? Bk0 : (m == 1) ? Bv0 : (m == 2) ? Bk1 : Bv1;
      float* bo = (m == 0) ? bk0 : (m == 1) ? bv0 : (m == 2) ? bk1 : bv1;
      float s = 0.0f;
#pragma unroll 8
      for (int j = 0; j < DD; ++j) s += bp[j] * B[j * DD + c];
      bo[c] = s;
    }
  } else {
    const int id = (b - 514) * 256 + t;
    if (id < 2 * NN) deg[id] = 0;
  }
}

// load x-row fragment (fp32 -> bf16): 32B/lane coalesced within 16-row group
__device__ __forceinline__ void load_xfrag(const float* __restrict__ x,
                                           int row, bool valid, int lane,
                                           bf16x8* a) {
  if (valid) {
    const float* xr = x + (size_t)row * DD + (lane >> 4) * 8;
#pragma unroll
    for (int kk = 0; kk < 4; ++kk) {
      const float4 f0 = *(const float4*)(xr + kk * 32);
      const float4 f1 = *(const float4*)(xr + kk * 32 + 4);
      a[kk][0] = (short)f2bf(f0.x); a[kk][1] = (short)f2bf(f0.y);
      a[kk][2] = (short)f2bf(f0.z); a[kk][3] = (short)f2bf(f0.w);
      a[kk][4] = (short)f2bf(f1.x); a[kk][5] = (short)f2bf(f1.y);
      a[kk][6] = (short)f2bf(f1.z); a[kk][7] = (short)f2bf(f1.w);
    }
  } else {
#pragma unroll
    for (int kk = 0; kk < 4; ++kk)
#pragma unroll
      for (int j = 0; j < 8; ++j) a[kk][j] = 0;
  }
}

// one wave, 16 rows x 128 cols via 8x4 mfma; bias preloaded in registers
__device__ __forceinline__ void mfma_tile_store_p(
    const unsigned short* WLw, const bf16x8* a, int lane, int rowbase,
    bool wvalid, const float* bias8, unsigned short* __restrict__ outb) {
  const int r0 = rowbase + (lane >> 4) * 4;
#pragma unroll
  for (int ni = 0; ni < 8; ++ni) {
    const int cl = ni * 16 + (lane & 15);
    f32x4 acc = {0.f, 0.f, 0.f, 0.f};
#pragma unroll
    for (int kk = 0; kk < 4; ++kk) {
      const int boff = cl * 256 + ((kk * 64 + (lane >> 4) * 16) ^ ((cl & 15) << 4));
      const bf16x8 bb = *(const bf16x8*)((const char*)WLw + boff);
      acc = __builtin_amdgcn_mfma_f32_16x16x32_bf16(a[kk], bb, acc, 0, 0, 0);
    }
    if (wvalid) {
      const float bv = bias8[ni];
#pragma unroll
      for (int r = 0; r < 4; ++r)
        outb[(size_t)(r0 + r) * DD + cl] = f2bf(acc[r] + bv);
    }
  }
}

// ---- persistent fused proj: 1 block/CU, 16 waves, all 3 Ws in 96KB LDS,
// ONE barrier total; waves grid-stride row-sets with zero further syncs.
// Degree count runs as per-block tail work (overlapped).
__global__ __launch_bounds__(1024) void fused_proj(
    const float* __restrict__ x0, const unsigned short* __restrict__ Wpt0,
    const float* __restrict__ bp0, const unsigned short* __restrict__ Wkta,
    const float* __restrict__ bka, const unsigned short* __restrict__ Wvta,
    const float* __restrict__ bva, unsigned short* __restrict__ h0,
    unsigned short* __restrict__ K0, unsigned short* __restrict__ V0,
    const float* __restrict__ x1, const unsigned short* __restrict__ Wpt1,
    const float* __restrict__ bp1, const unsigned short* __restrict__ Wktb,
    const float* __restrict__ bkb, const unsigned short* __restrict__ Wvtb,
    const float* __restrict__ bvb, unsigned short* __restrict__ h1,
    unsigned short* __restrict__ K1, unsigned short* __restrict__ V1,
    const int* __restrict__ ei0, const int* __restrict__ ei1,
    int* __restrict__ deg) {
  __shared__ unsigned short WL[3 * DD * DD];   // 96 KB
  const int bid = blockIdx.x;
  const bool second = bid >= PBH;
  const int tb = second ? bid - PBH : bid;
  const float* x = second ? x1 : x0;
  const unsigned short* Ws0 = second ? Wpt1 : Wpt0;
  const unsigned short* Ws1 = second ? Wktb : Wkta;
  const unsigned short* Ws2 = second ? Wvtb : Wvta;
  const float* bs0 = second ? bp1 : bp0;
  const float* bs1 = second ? bkb : bka;
  const float* bs2 = second ? bvb : bva;
  unsigned short* out0 = second ? h1 : h0;
  unsigned short* out1 = second ? K1 : K0;
  unsigned short* out2 = second ? V1 : V0;

  const int tid = threadIdx.x, lane = tid & 63, wid = tid >> 6;  // wid 0..15
  // stage all three Ws (swizzled), once
  {
    const float4* s0 = (const float4*)Ws0;
    const float4* s1 = (const float4*)Ws1;
    const float4* s2 = (const float4*)Ws2;
#pragma unroll
    for (int i = 0; i < 2; ++i) {
      const int idx = tid + i * 1024;
      const int L = idx * 16;
      const int Ls = L ^ (((L >> 8) & 15) << 4);
      *(float4*)((char*)WL + Ls) = s0[idx];
      *(float4*)((char*)(WL + DD * DD) + Ls) = s1[idx];
      *(float4*)((char*)(WL + 2 * DD * DD) + Ls) = s2[idx];
    }
  }
  // preload per-thread biases (cl = ni*16 + (lane&15))
  float b8a[8], b8b[8], b8c[8];
#pragma unroll
  for (int ni = 0; ni < 8; ++ni) {
    const int cl = ni * 16 + (lane & 15);
    b8a[ni] = bs0[cl];
    b8b[ni] = bs1[cl];
    b8c[ni] = bs2[cl];
  }
  __syncthreads();   // the only barrier

  const int nrt = (NN + 255) / 256;   // 391 row-tiles of 256 rows
  for (int rt = tb; rt < nrt; rt += PBH) {
    const int rowbase = rt * 256 + wid * 16;
    const bool wvalid = rowbase < NN;   // NN % 16 == 0 -> whole-wave validity
    bf16x8 a[4];
    load_xfrag(x, rowbase + (lane & 15), wvalid, lane, a);
    mfma_tile_store_p(WL, a, lane, rowbase, wvalid, b8a, out0);
    mfma_tile_store_p(WL + DD * DD, a, lane, rowbase, wvalid, b8b, out1);
    mfma_tile_store_p(WL + 2 * DD * DD, a, lane, rowbase, wvalid, b8c, out2);
  }

  // tail: degree count (independent; overlaps other blocks' proj work)
  for (int e = bid * 1024 + tid; e < 2 * EE; e += PB * 1024) {
    const int d = (e < EE) ? ei0[EE + e] : (NN + ei1[e]);
    atomicAdd(&deg[d], 1);
  }
}

// ---- fused update GEMM + skip + LayerNorm + ReLU, R12 structure (unchanged)
__global__ __launch_bounds__(256) void update_ln2(
    const unsigned short* __restrict__ hA, const unsigned short* __restrict__ aggA,
    const unsigned short* __restrict__ WutA, const float* __restrict__ buA,
    const float* __restrict__ gA, const float* __restrict__ beA,
    float* __restrict__ outA,
    const unsigned short* __restrict__ hB, const unsigned short* __restrict__ aggB,
    const unsigned short* __restrict__ WutB, const float* __restrict__ buB,
    const float* __restrict__ gB, const float* __restrict__ beB,
    float* __restrict__ outB, int half) {
  __shared__ unsigned short WL[DD * DD];
  int bid = blockIdx.x;
  const bool second = bid >= half;
  if (second) bid -= half;
  const unsigned short* h = second ? hB : hA;
  const unsigned short* agg = second ? aggB : aggA;
  const unsigned short* Wut = second ? WutB : WutA;
  const float* bu = second ? buB : buA;
  const float* g = second ? gB : gA;
  const float* be = second ? beB : beA;
  float* out = second ? outB : outA;

  const int tid = threadIdx.x, lane = tid & 63, wid = tid >> 6;
  const int rowbase = bid * 64 + wid * 16;
  const bool wvalid = rowbase < NN;
  bf16x8 a[4];
  if (wvalid) {
    const int arow = rowbase + (lane & 15);
#pragma unroll
    for (int kk = 0; kk < 4; ++kk)
      a[kk] = *(const bf16x8*)(agg + (size_t)arow * DD + kk * 32 + (lane >> 4) * 8);
  } else {
#pragma unroll
    for (int kk = 0; kk < 4; ++kk)
#pragma unroll
      for (int j = 0; j < 8; ++j) a[kk][j] = 0;
  }
#pragma unroll
  for (int i_ = tid; i_ < 2048; i_ += 256) {
    const int L_ = i_ * 16;
    *(float4*)((char*)WL + (L_ ^ (((L_ >> 8) & 15) << 4))) =
        ((const float4*)Wut)[i_];
  }
  __syncthreads();
  f32x4 acc[8];
  const int r0 = rowbase + (lane >> 4) * 4;
#pragma unroll
  for (int ni = 0; ni < 8; ++ni) {
    const int cl = ni * 16 + (lane & 15);
    acc[ni] = (f32x4){0.f, 0.f, 0.f, 0.f};
#pragma unroll
    for (int kk = 0; kk < 4; ++kk) {
      const int boff = cl * 256 + ((kk * 64 + (lane >> 4) * 16) ^ ((cl & 15) << 4));
      const bf16x8 bb = *(const bf16x8*)((const char*)WL + boff);
      acc[ni] = __builtin_amdgcn_mfma_f32_16x16x32_bf16(a[kk], bb, acc[ni], 0, 0, 0);
    }
  }
  if (!wvalid) return;
#pragma unroll
  for (int ni = 0; ni < 8; ++ni) {
    const int cl = ni * 16 + (lane & 15);
    const float bv = bu[cl];
#pragma unroll
    for (int r = 0; r < 4; ++r)
      acc[ni][r] += bf2f(h[(size_t)(r0 + r) * DD + cl]) + bv;
  }
  float mean[4], inv[4];
#pragma unroll
  for (int r = 0; r < 4; ++r) {
    float s = 0.f, q = 0.f;
#pragma unroll
    for (int ni = 0; ni < 8; ++ni) {
      const float v = acc[ni][r];
      s += v; q += v * v;
    }
    s += __shfl_xor(s, 1); q += __shfl_xor(q, 1);
    s += __shfl_xor(s, 2); q += __shfl_xor(q, 2);
    s += __shfl_xor(s, 4); q += __shfl_xor(q, 4);
    s += __shfl_xor(s, 8); q += __shfl_xor(q, 8);
    const float mu = s * (1.0f / 128.0f);
    mean[r] = mu;
    inv[r] = rsqrtf(q * (1.0f / 128.0f) - mu * mu + 1e-5f);
  }
#pragma unroll
  for (int ni = 0; ni < 8; ++ni) {
    const int cl = ni * 16 + (lane & 15);
    const float gv = g[cl], bev = be[cl];
#pragma unroll
    for (int r = 0; r < 4; ++r)
      out[(size_t)(r0 + r) * DD + cl] =
          fmaxf((acc[ni][r] - mean[r]) * inv[r] * gv + bev, 0.0f);
  }
}

// ---------------- CSR scan chain (deg counted inside fused_proj)
__global__ __launch_bounds__(256) void scan1(const int* __restrict__ deg,
                                             int* __restrict__ excl,
                                             int* __restrict__ partials, int n) {
  __shared__ int ls[256];
  const int b0 = blockIdx.x * 1024;
  const int t = threadIdx.x;
  int v[4];
  int s = 0;
#pragma unroll
  for (int i = 0; i < 4; ++i) {
    const int idx = b0 + t * 4 + i;
    v[i] = (idx < n) ? deg[idx] : 0;
    s += v[i];
  }
  ls[t] = s;
  __syncthreads();
  for (int off = 1; off < 256; off <<= 1) {
    const int x = (t >= off) ? ls[t - off] : 0;
    __syncthreads();
    ls[t] += x;
    __syncthreads();
  }
  int ex = ls[t] - s;
#pragma unroll
  for (int i = 0; i < 4; ++i) {
    const int idx = b0 + t * 4 + i;
    if (idx < n) excl[idx] = ex;
    ex += v[i];
  }
  if (t == 255) partials[blockIdx.x] = ls[255];
}

__global__ __launch_bounds__(256) void scan2(int* __restrict__ partials, int nb) {
  __shared__ int ls[256];
  const int t = threadIdx.x;
  const int v = (t < nb) ? partials[t] : 0;
  ls[t] = v;
  __syncthreads();
  for (int off = 1; off < 256; off <<= 1) {
    const int x = (t >= off) ? ls[t - off] : 0;
    __syncthreads();
    ls[t] += x;
    __syncthreads();
  }
  if (t < nb) partials[t] = ls[t] - v;
}

__global__ __launch_bounds__(256) void scan3(const int* __restrict__ excl,
                                             const int* __restrict__ partials,
                                             int n, int* __restrict__ rowptr) {
  const int i = blockIdx.x * 256 + threadIdx.x;
  if (i < n) rowptr[i] = excl[i] + partials[i >> 10];
}

// fill: atomic bump rowptr itself; afterwards rowptr[d] == end(d)
__global__ __launch_bounds__(256) void fill_csr2(const int* __restrict__ ei0,
                                                 const int* __restrict__ ei1,
                                                 int* __restrict__ rowptr,
                                                 int* __restrict__ csr_src) {
  const int e = blockIdx.x * 256 + threadIdx.x;
  if (e >= 2 * EE) return;
  int s, d;
  if (e < EE) { s = ei0[e]; d = ei0[EE + e]; }
  else        { s = ei1[e - EE]; d = NN + ei1[e]; }
  const int p = atomicAdd(&rowptr[d], 1);
  csr_src[p] = s;
}

// ---- per-destination attention, 4 edges in flight per wave (16-lane groups).
// 32-bit byte offsets for K/V gathers (one shift per edge serves both).
__global__ __launch_bounds__(256) void dst_attention(
    const unsigned short* __restrict__ Hq0, const unsigned short* __restrict__ K0,
    const unsigned short* __restrict__ V0, unsigned short* __restrict__ agg0,
    const unsigned short* __restrict__ Hq1, const unsigned short* __restrict__ K1,
    const unsigned short* __restrict__ V1, unsigned short* __restrict__ agg1,
    const int* __restrict__ rowptr, const int* __restrict__ deg,
    const int* __restrict__ csr_src) {
  const int gw = blockIdx.x * 4 + (threadIdx.x >> 6);
  if (gw >= 2 * NN) return;
  const bool rel1 = gw >= NN;
  const int node = rel1 ? gw - NN : gw;
  const unsigned short* Hq = rel1 ? Hq1 : Hq0;
  const char* Kb = (const char*)(rel1 ? K1 : K0);
  const char* Vb = (const char*)(rel1 ? V1 : V0);
  unsigned short* agg = rel1 ? agg1 : agg0;

  const int lane = threadIdx.x & 63;
  const int sub = lane & 15;   // dims [sub*8, sub*8+8)
  const int grp = lane >> 4;   // edge group 0..3
  const unsigned lboff = (unsigned)sub << 4;   // lane byte offset within row
  const int end = rowptr[gw];
  const int beg = end - deg[gw];
  const uint4 qu = *(const uint4*)(Hq + (size_t)node * DD + sub * 8);
#if defined(HAVE_FDOT2)
  const bf16x2t q0 = __builtin_bit_cast(bf16x2t, qu.x);
  const bf16x2t q1 = __builtin_bit_cast(bf16x2t, qu.y);
  const bf16x2t q2 = __builtin_bit_cast(bf16x2t, qu.z);
  const bf16x2t q3 = __builtin_bit_cast(bf16x2t, qu.w);
#else
  float qf[8];
  qf[0] = bf2f((unsigned short)qu.x); qf[1] = bf2f((unsigned short)(qu.x >> 16));
  qf[2] = bf2f((unsigned short)qu.y); qf[3] = bf2f((unsigned short)(qu.y >> 16));
  qf[4] = bf2f((unsigned short)qu.z); qf[5] = bf2f((unsigned short)(qu.z >> 16));
  qf[6] = bf2f((unsigned short)qu.w); qf[7] = bf2f((unsigned short)(qu.w >> 16));
#endif
  float av[8] = {0.f, 0.f, 0.f, 0.f, 0.f, 0.f, 0.f, 0.f};
  float lsum = 0.0f;
  for (int i = beg + grp; i < end; i += 4) {
    const unsigned roff = ((unsigned)csr_src[i] << 8) + lboff;
    const uint4 kp = *(const uint4*)(Kb + roff);
#if defined(HAVE_FDOT2)
    float p = __builtin_amdgcn_fdot2_f32_bf16(__builtin_bit_cast(bf16x2t, kp.x), q0, 0.0f, false);
    p = __builtin_amdgcn_fdot2_f32_bf16(__builtin_bit_cast(bf16x2t, kp.y), q1, p, false);
    p = __builtin_amdgcn_fdot2_f32_bf16(__builtin_bit_cast(bf16x2t, kp.z), q2, p, false);
    p = __builtin_amdgcn_fdot2_f32_bf16(__builtin_bit_cast(bf16x2t, kp.w), q3, p, false);
#else
    float p;
    p  = qf[0] * bf2f((unsigned short)kp.x) + qf[1] * bf2f((unsigned short)(kp.x >> 16));
    p += qf[2] * bf2f((unsigned short)kp.y) + qf[3] * bf2f((unsigned short)(kp.y >> 16));
    p += qf[4] * bf2f((unsigned short)kp.z) + qf[5] * bf2f((unsigned short)(kp.z >> 16));
    p += qf[6] * bf2f((unsigned short)kp.w) + qf[7] * bf2f((unsigned short)(kp.w >> 16));
#endif
    p += __shfl_xor(p, 1);
    p += __shfl_xor(p, 2);
    const float wgt = __expf(p * 0.17677669529663689f);  // 1/sqrt(32)
    const uint4 vp = *(const uint4*)(Vb + roff);
    lsum += wgt;
    av[0] += wgt * __uint_as_float(vp.x << 16);
    av[1] += wgt * __uint_as_float(vp.x & 0xFFFF0000u);
    av[2] += wgt * __uint_as_float(vp.y << 16);
    av[3] += wgt * __uint_as_float(vp.y & 0xFFFF0000u);
    av[4] += wgt * __uint_as_float(vp.z << 16);
    av[5] += wgt * __uint_as_float(vp.z & 0xFFFF0000u);
    av[6] += wgt * __uint_as_float(vp.w << 16);
    av[7] += wgt * __uint_as_float(vp.w & 0xFFFF0000u);
  }
#pragma unroll
  for (int d = 0; d < 8; ++d) {
    av[d] += __shfl_xor(av[d], 16);
    av[d] += __shfl_xor(av[d], 32);
  }
  lsum += __shfl_xor(lsum, 16);
  lsum += __shfl_xor(lsum, 32);
  if (grp == 0) {
    const float invl = (lsum > 0.0f) ? (1.0f / lsum) : 0.0f;
    uint4 o;
    o.x = (unsigned)f2bf(av[0] * invl) | ((unsigned)f2bf(av[1] * invl) << 16);
    o.y = (unsigned)f2bf(av[2] * invl) | ((unsigned)f2bf(av[3] * invl) << 16);
    o.z = (unsigned)f2bf(av[4] * invl) | ((unsigned)f2bf(av[5] * invl) << 16);
    o.w = (unsigned)f2bf(av[6] * invl) | ((unsigned)f2bf(av[7] * invl) << 16);
    *(uint4*)(agg + (size_t)node * DD + sub * 8) = o;
  }
}

extern "C" void kernel_launch(void* const* d_in, const int* in_sizes, int n_in,
                              void* d_out, int out_size, void* d_ws, size_t ws_size,
                              hipStream_t stream) {
  const float* x_drug  = (const float*)d_in[0];
  const float* x_dis   = (const float*)d_in[1];
  const float* Wp_drug = (const float*)d_in[2];
  const float* bp_drug = (const float*)d_in[3];
  const float* Wp_dis  = (const float*)d_in[4];
  const float* bp_dis  = (const float*)d_in[5];
  const float* Wk_r0   = (const float*)d_in[6];
  const float* Wv_r0   = (const float*)d_in[7];
  const float* Wk_r1   = (const float*)d_in[8];
  const float* Wv_r1   = (const float*)d_in[9];
  const float* Wu_drug = (const float*)d_in[10];
  const float* bu_drug = (const float*)d_in[11];
  const float* Wu_dis  = (const float*)d_in[12];
  const float* bu_dis  = (const float*)d_in[13];
  const float* g_drug  = (const float*)d_in[14];
  const float* be_drug = (const float*)d_in[15];
  const float* g_dis   = (const float*)d_in[16];
  const float* be_dis  = (const float*)d_in[17];
  const int* ei_r0     = (const int*)d_in[18];
  const int* ei_r1     = (const int*)d_in[19];

  float* out = (float*)d_out;
  float* out_drug = out;
  float* out_dis  = out + (size_t)NN * DD;

  const size_t ND = (size_t)NN * DD;
  char* w = (char*)d_ws;
  unsigned short* Kr0  = (unsigned short*)w; w += ND * 2;
  unsigned short* Vr0  = (unsigned short*)w; w += ND * 2;
  unsigned short* Kr1  = (unsigned short*)w; w += ND * 2;
  unsigned short* Vr1  = (unsigned short*)w; w += ND * 2;
  unsigned short* agdr = (unsigned short*)w; w += ND * 2;
  unsigned short* agdi = (unsigned short*)w; w += ND * 2;
  unsigned short* hb_dr = (unsigned short*)w; w += ND * 2;
  unsigned short* hb_di = (unsigned short*)w; w += ND * 2;
  unsigned short* Wpt_dr = (unsigned short*)w; w += DD * DD * 2;
  unsigned short* Wpt_di = (unsigned short*)w; w += DD * DD * 2;
  unsigned short* Wut_dr = (unsigned short*)w; w += DD * DD * 2;
  unsigned short* Wut_di = (unsigned short*)w; w += DD * DD * 2;
  unsigned short* Wkt0 = (unsigned short*)w; w += DD * DD * 2;
  unsigned short* Wvt0 = (unsigned short*)w; w += DD * DD * 2;
  unsigned short* Wkt1 = (unsigned short*)w; w += DD * DD * 2;
  unsigned short* Wvt1 = (unsigned short*)w; w += DD * DD * 2;
  float* bk0 = (float*)w; w += DD * 4;
  float* bv0 = (float*)w; w += DD * 4;
  float* bk1 = (float*)w; w += DD * 4;
  float* bv1 = (float*)w; w += DD * 4;
  int* deg      = (int*)w; w += 2 * NN * 4;
  int* excl     = (int*)w; w += 2 * NN * 4;
  int* rowptr   = (int*)w; w += (2 * NN + 1) * 4;
  int* partials = (int*)w; w += 256 * 4;
  int* csr_src  = (int*)w; w += 2 * EE * 4;

  const int gemm_blocks = (NN + 63) / 64;            // 1563
  const int cnt_blocks = (2 * EE + 255) / 256;       // 3125 (fill)
  const int nchunks = (2 * NN + 1023) / 1024;        // 196
  const int n256 = (2 * NN + 255) / 256;             // 782
  const int attn_blocks = (2 * NN + 3) / 4;          // 50000
  const int zero_blocks = (2 * NN + 255) / 256;      // 782
  dim3 b256(256), b1024(1024);

  // weight prep + deg zeroing in one launch
  prep_weights<<<514 + zero_blocks, b256, 0, stream>>>(
      Wp_drug, bp_drug, Wp_dis, bp_dis, Wu_drug, Wu_dis,
      Wk_r0, Wv_r0, Wk_r1, Wv_r1,
      Wpt_dr, Wpt_di, Wut_dr, Wut_di,
      Wkt0, bk0, Wvt0, bv0, Wkt1, bk1, Wvt1, bv1, deg);

  // persistent projections (1 block/CU) with degree-count tail
  fused_proj<<<PB, b1024, 0, stream>>>(
      x_drug, Wpt_dr, bp_drug, Wkt0, bk0, Wvt0, bv0, hb_dr, Kr0, Vr0,
      x_dis,  Wpt_di, bp_dis,  Wkt1, bk1, Wvt1, bv1, hb_di, Kr1, Vr1,
      ei_r0, ei_r1, deg);

  scan1<<<nchunks, b256, 0, stream>>>(deg, excl, partials, 2 * NN);
  scan2<<<1, b256, 0, stream>>>(partials, nchunks);
  scan3<<<n256, b256, 0, stream>>>(excl, partials, 2 * NN, rowptr);
  fill_csr2<<<cnt_blocks, b256, 0, stream>>>(ei_r0, ei_r1, rowptr, csr_src);

  dst_attention<<<attn_blocks, b256, 0, stream>>>(
      hb_di, Kr0, Vr0, agdi,          // rel0: dst = dis
      hb_dr, Kr1, Vr1, agdr,          // rel1: dst = drug
      rowptr, deg, csr_src);

  update_ln2<<<2 * gemm_blocks, b256, 0, stream>>>(
      hb_dr, agdr, Wut_dr, bu_drug, g_drug, be_drug, out_drug,
      hb_di, agdi, Wut_di, bu_dis,  g_dis,  be_dis,  out_dis,
      gemm_blocks);
}

// Round 16
// 501.492 us; speedup vs baseline: 1.4242x; 1.4242x over previous
//
#include <hip/hip_runtime.h>
#include <math.h>

#define NN 100000
#define EE 400000
#define DD 128
#define PB 256    // persistent proj blocks (1/CU)
#define PBH 128   // per node type

typedef __attribute__((ext_vector_type(8))) short bf16x8;
typedef __attribute__((ext_vector_type(4))) float f32x4;

#if defined(__has_builtin)
#if __has_builtin(__builtin_amdgcn_fdot2_f32_bf16)
#define HAVE_FDOT2 1
typedef __attribute__((ext_vector_type(2))) __bf16 bf16x2t;
#endif
#endif

__device__ __forceinline__ unsigned short f2bf(float f) {
  unsigned u = __float_as_uint(f);
  u += 0x7FFF + ((u >> 16) & 1);   // round-to-nearest-even
  return (unsigned short)(u >> 16);
}
__device__ __forceinline__ float bf2f(unsigned short u) {
  return __uint_as_float(((unsigned)u) << 16);
}

// ---- one-shot weight prep (+ deg zeroing appended as extra blocks)
__global__ __launch_bounds__(256) void prep_weights(
    const float* __restrict__ Wp_dr, const float* __restrict__ bp_dr,
    const float* __restrict__ Wp_di, const float* __restrict__ bp_di,
    const float* __restrict__ Wu_dr, const float* __restrict__ Wu_di,
    const float* __restrict__ Bk0, const float* __restrict__ Bv0,
    const float* __restrict__ Bk1, const float* __restrict__ Bv1,
    unsigned short* __restrict__ Wpt_dr, unsigned short* __restrict__ Wpt_di,
    unsigned short* __restrict__ Wut_dr, unsigned short* __restrict__ Wut_di,
    unsigned short* __restrict__ Wkt0, float* __restrict__ bk0,
    unsigned short* __restrict__ Wvt0, float* __restrict__ bv0,
    unsigned short* __restrict__ Wkt1, float* __restrict__ bk1,
    unsigned short* __restrict__ Wvt1, float* __restrict__ bv1,
    int* __restrict__ deg) {
  const int b = blockIdx.x, t = threadIdx.x;
  if (b < 256) {
    const int id = b * 256 + t;
    const int m = id >> 14, rem = id & 16383, k = rem & 127, c = rem >> 7;
    const float* W = (m == 0) ? Wp_dr : (m == 1) ? Wp_di : (m == 2) ? Wu_dr : Wu_di;
    unsigned short* O = (m == 0) ? Wpt_dr : (m == 1) ? Wpt_di : (m == 2) ? Wut_dr : Wut_di;
    O[c * DD + k] = f2bf(W[(size_t)k * DD + c]);
  } else if (b < 512) {
    const int id = (b - 256) * 256 + t;
    const int m = id >> 14, rem = id & 16383, k = rem & 127, c = rem >> 7;
    const float* A = (m < 2) ? Wp_dr : Wp_di;
    const float* B = (m == 0) ? Bk0 : (m == 1) ? Bv0 : (m == 2) ? Bk1 : Bv1;
    unsigned short* O = (m == 0) ? Wkt0 : (m == 1) ? Wvt0 : (m == 2) ? Wkt1 : Wvt1;
    const float4* a4 = (const float4*)(A + (size_t)k * DD);
    float s = 0.0f;
#pragma unroll 8
    for (int j4 = 0; j4 < 32; ++j4) {
      const float4 av = a4[j4];
      s += av.x * B[(4 * j4 + 0) * DD + c] + av.y * B[(4 * j4 + 1) * DD + c]
         + av.z * B[(4 * j4 + 2) * DD + c] + av.w * B[(4 * j4 + 3) * DD + c];
    }
    O[c * DD + k] = f2bf(s);
  } else if (b < 514) {
    const int id = (b - 512) * 256 + t;
    if (id < 512) {
      const int m = id >> 7, c = id & 127;
      const float* bp = (m < 2) ? bp_dr : bp_di;
      const float* B = (m == 0) ? Bk0 : (m == 1) ? Bv0 : (m == 2) ? Bk1 : Bv1;
      float* bo = (m == 0) ? bk0 : (m == 1) ? bv0 : (m == 2) ? bk1 : bv1;
      float s = 0.0f;
#pragma unroll 8
      for (int j = 0; j < DD; ++j) s += bp[j] * B[j * DD + c];
      bo[c] = s;
    }
  } else {
    const int id = (b - 514) * 256 + t;
    if (id < 2 * NN) deg[id] = 0;
  }
}

// load x-row fragment (fp32 -> bf16): 32B/lane coalesced within 16-row group
__device__ __forceinline__ void load_xfrag(const float* __restrict__ x,
                                           int row, bool valid, int lane,
                                           bf16x8* a) {
  if (valid) {
    const float* xr = x + (size_t)row * DD + (lane >> 4) * 8;
#pragma unroll
    for (int kk = 0; kk < 4; ++kk) {
      const float4 f0 = *(const float4*)(xr + kk * 32);
      const float4 f1 = *(const float4*)(xr + kk * 32 + 4);
      a[kk][0] = (short)f2bf(f0.x); a[kk][1] = (short)f2bf(f0.y);
      a[kk][2] = (short)f2bf(f0.z); a[kk][3] = (short)f2bf(f0.w);
      a[kk][4] = (short)f2bf(f1.x); a[kk][5] = (short)f2bf(f1.y);
      a[kk][6] = (short)f2bf(f1.z); a[kk][7] = (short)f2bf(f1.w);
    }
  } else {
#pragma unroll
    for (int kk = 0; kk < 4; ++kk)
#pragma unroll
      for (int j = 0; j < 8; ++j) a[kk][j] = 0;
  }
}

// one wave, 16 rows x 128 cols via 8x4 mfma; bias preloaded in registers
__device__ __forceinline__ void mfma_tile_store_p(
    const unsigned short* WLw, const bf16x8* a, int lane, int rowbase,
    bool wvalid, const float* bias8, unsigned short* __restrict__ outb) {
  const int r0 = rowbase + (lane >> 4) * 4;
#pragma unroll
  for (int ni = 0; ni < 8; ++ni) {
    const int cl = ni * 16 + (lane & 15);
    f32x4 acc = {0.f, 0.f, 0.f, 0.f};
#pragma unroll
    for (int kk = 0; kk < 4; ++kk) {
      const int boff = cl * 256 + ((kk * 64 + (lane >> 4) * 16) ^ ((cl & 15) << 4));
      const bf16x8 bb = *(const bf16x8*)((const char*)WLw + boff);
      acc = __builtin_amdgcn_mfma_f32_16x16x32_bf16(a[kk], bb, acc, 0, 0, 0);
    }
    if (wvalid) {
      const float bv = bias8[ni];
#pragma unroll
      for (int r = 0; r < 4; ++r)
        outb[(size_t)(r0 + r) * DD + cl] = f2bf(acc[r] + bv);
    }
  }
}

// ---- persistent fused proj: 1 block/CU, 8 waves (512 thr -> 128 VGPR cap,
// no spills), all 3 Ws in 96KB LDS staged ONCE, one barrier total; waves
// grid-stride 128-row tiles with zero further syncs. Degree-count tail.
__global__ __launch_bounds__(512) void fused_proj(
    const float* __restrict__ x0, const unsigned short* __restrict__ Wpt0,
    const float* __restrict__ bp0, const unsigned short* __restrict__ Wkta,
    const float* __restrict__ bka, const unsigned short* __restrict__ Wvta,
    const float* __restrict__ bva, unsigned short* __restrict__ h0,
    unsigned short* __restrict__ K0, unsigned short* __restrict__ V0,
    const float* __restrict__ x1, const unsigned short* __restrict__ Wpt1,
    const float* __restrict__ bp1, const unsigned short* __restrict__ Wktb,
    const float* __restrict__ bkb, const unsigned short* __restrict__ Wvtb,
    const float* __restrict__ bvb, unsigned short* __restrict__ h1,
    unsigned short* __restrict__ K1, unsigned short* __restrict__ V1,
    const int* __restrict__ ei0, const int* __restrict__ ei1,
    int* __restrict__ deg) {
  __shared__ unsigned short WL[3 * DD * DD];   // 96 KB
  const int bid = blockIdx.x;
  const bool second = bid >= PBH;
  const int tb = second ? bid - PBH : bid;
  const float* x = second ? x1 : x0;
  const unsigned short* Ws0 = second ? Wpt1 : Wpt0;
  const unsigned short* Ws1 = second ? Wktb : Wkta;
  const unsigned short* Ws2 = second ? Wvtb : Wvta;
  const float* bs0 = second ? bp1 : bp0;
  const float* bs1 = second ? bkb : bka;
  const float* bs2 = second ? bvb : bva;
  unsigned short* out0 = second ? h1 : h0;
  unsigned short* out1 = second ? K1 : K0;
  unsigned short* out2 = second ? V1 : V0;

  const int tid = threadIdx.x, lane = tid & 63, wid = tid >> 6;  // wid 0..7
  // stage all three Ws (swizzled), once per block
  {
    const float4* s0 = (const float4*)Ws0;
    const float4* s1 = (const float4*)Ws1;
    const float4* s2 = (const float4*)Ws2;
#pragma unroll
    for (int i = 0; i < 4; ++i) {
      const int idx = tid + i * 512;
      const int L = idx * 16;
      const int Ls = L ^ (((L >> 8) & 15) << 4);
      *(float4*)((char*)WL + Ls) = s0[idx];
      *(float4*)((char*)(WL + DD * DD) + Ls) = s1[idx];
      *(float4*)((char*)(WL + 2 * DD * DD) + Ls) = s2[idx];
    }
  }
  // preload per-thread biases (cl = ni*16 + (lane&15))
  float b8a[8], b8b[8], b8c[8];
#pragma unroll
  for (int ni = 0; ni < 8; ++ni) {
    const int cl = ni * 16 + (lane & 15);
    b8a[ni] = bs0[cl];
    b8b[ni] = bs1[cl];
    b8c[ni] = bs2[cl];
  }
  __syncthreads();   // the only barrier

  const int nrt = (NN + 127) / 128;   // 782 row-tiles of 128 rows
  for (int rt = tb; rt < nrt; rt += PBH) {
    const int rowbase = rt * 128 + wid * 16;
    const bool wvalid = rowbase < NN;
    bf16x8 a[4];
    load_xfrag(x, rowbase + (lane & 15), wvalid, lane, a);
    mfma_tile_store_p(WL, a, lane, rowbase, wvalid, b8a, out0);
    mfma_tile_store_p(WL + DD * DD, a, lane, rowbase, wvalid, b8b, out1);
    mfma_tile_store_p(WL + 2 * DD * DD, a, lane, rowbase, wvalid, b8c, out2);
  }

  // tail: degree count (independent; overlaps other blocks' proj work)
  for (int e = bid * 512 + tid; e < 2 * EE; e += PB * 512) {
    const int d = (e < EE) ? ei0[EE + e] : (NN + ei1[e]);
    atomicAdd(&deg[d], 1);
  }
}

// ---- fused update GEMM + skip + LayerNorm + ReLU, R12 structure (unchanged)
__global__ __launch_bounds__(256) void update_ln2(
    const unsigned short* __restrict__ hA, const unsigned short* __restrict__ aggA,
    const unsigned short* __restrict__ WutA, const float* __restrict__ buA,
    const float* __restrict__ gA, const float* __restrict__ beA,
    float* __restrict__ outA,
    const unsigned short* __restrict__ hB, const unsigned short* __restrict__ aggB,
    const unsigned short* __restrict__ WutB, const float* __restrict__ buB,
    const float* __restrict__ gB, const float* __restrict__ beB,
    float* __restrict__ outB, int half) {
  __shared__ unsigned short WL[DD * DD];
  int bid = blockIdx.x;
  const bool second = bid >= half;
  if (second) bid -= half;
  const unsigned short* h = second ? hB : hA;
  const unsigned short* agg = second ? aggB : aggA;
  const unsigned short* Wut = second ? WutB : WutA;
  const float* bu = second ? buB : buA;
  const float* g = second ? gB : gA;
  const float* be = second ? beB : beA;
  float* out = second ? outB : outA;

  const int tid = threadIdx.x, lane = tid & 63, wid = tid >> 6;
  const int rowbase = bid * 64 + wid * 16;
  const bool wvalid = rowbase < NN;
  bf16x8 a[4];
  if (wvalid) {
    const int arow = rowbase + (lane & 15);
#pragma unroll
    for (int kk = 0; kk < 4; ++kk)
      a[kk] = *(const bf16x8*)(agg + (size_t)arow * DD + kk * 32 + (lane >> 4) * 8);
  } else {
#pragma unroll
    for (int kk = 0; kk < 4; ++kk)
#pragma unroll
      for (int j = 0; j < 8; ++j) a[kk][j] = 0;
  }
#pragma unroll
  for (int i_ = tid; i_ < 2048; i_ += 256) {
    const int L_ = i_ * 16;
    *(float4*)((char*)WL + (L_ ^ (((L_ >> 8) & 15) << 4))) =
        ((const float4*)Wut)[i_];
  }
  __syncthreads();
  f32x4 acc[8];
  const int r0 = rowbase + (lane >> 4) * 4;
#pragma unroll
  for (int ni = 0; ni < 8; ++ni) {
    const int cl = ni * 16 + (lane & 15);
    acc[ni] = (f32x4){0.f, 0.f, 0.f, 0.f};
#pragma unroll
    for (int kk = 0; kk < 4; ++kk) {
      const int boff = cl * 256 + ((kk * 64 + (lane >> 4) * 16) ^ ((cl & 15) << 4));
      const bf16x8 bb = *(const bf16x8*)((const char*)WL + boff);
      acc[ni] = __builtin_amdgcn_mfma_f32_16x16x32_bf16(a[kk], bb, acc[ni], 0, 0, 0);
    }
  }
  if (!wvalid) return;
#pragma unroll
  for (int ni = 0; ni < 8; ++ni) {
    const int cl = ni * 16 + (lane & 15);
    const float bv = bu[cl];
#pragma unroll
    for (int r = 0; r < 4; ++r)
      acc[ni][r] += bf2f(h[(size_t)(r0 + r) * DD + cl]) + bv;
  }
  float mean[4], inv[4];
#pragma unroll
  for (int r = 0; r < 4; ++r) {
    float s = 0.f, q = 0.f;
#pragma unroll
    for (int ni = 0; ni < 8; ++ni) {
      const float v = acc[ni][r];
      s += v; q += v * v;
    }
    s += __shfl_xor(s, 1); q += __shfl_xor(q, 1);
    s += __shfl_xor(s, 2); q += __shfl_xor(q, 2);
    s += __shfl_xor(s, 4); q += __shfl_xor(q, 4);
    s += __shfl_xor(s, 8); q += __shfl_xor(q, 8);
    const float mu = s * (1.0f / 128.0f);
    mean[r] = mu;
    inv[r] = rsqrtf(q * (1.0f / 128.0f) - mu * mu + 1e-5f);
  }
#pragma unroll
  for (int ni = 0; ni < 8; ++ni) {
    const int cl = ni * 16 + (lane & 15);
    const float gv = g[cl], bev = be[cl];
#pragma unroll
    for (int r = 0; r < 4; ++r)
      out[(size_t)(r0 + r) * DD + cl] =
          fmaxf((acc[ni][r] - mean[r]) * inv[r] * gv + bev, 0.0f);
  }
}

// ---------------- CSR scan chain (deg counted inside fused_proj)
__global__ __launch_bounds__(256) void scan1(const int* __restrict__ deg,
                                             int* __restrict__ excl,
                                             int* __restrict__ partials, int n) {
  __shared__ int ls[256];
  const int b0 = blockIdx.x * 1024;
  const int t = threadIdx.x;
  int v[4];
  int s = 0;
#pragma unroll
  for (int i = 0; i < 4; ++i) {
    const int idx = b0 + t * 4 + i;
    v[i] = (idx < n) ? deg[idx] : 0;
    s += v[i];
  }
  ls[t] = s;
  __syncthreads();
  for (int off = 1; off < 256; off <<= 1) {
    const int x = (t >= off) ? ls[t - off] : 0;
    __syncthreads();
    ls[t] += x;
    __syncthreads();
  }
  int ex = ls[t] - s;
#pragma unroll
  for (int i = 0; i < 4; ++i) {
    const int idx = b0 + t * 4 + i;
    if (idx < n) excl[idx] = ex;
    ex += v[i];
  }
  if (t == 255) partials[blockIdx.x] = ls[255];
}

__global__ __launch_bounds__(256) void scan2(int* __restrict__ partials, int nb) {
  __shared__ int ls[256];
  const int t = threadIdx.x;
  const int v = (t < nb) ? partials[t] : 0;
  ls[t] = v;
  __syncthreads();
  for (int off = 1; off < 256; off <<= 1) {
    const int x = (t >= off) ? ls[t - off] : 0;
    __syncthreads();
    ls[t] += x;
    __syncthreads();
  }
  if (t < nb) partials[t] = ls[t] - v;
}

__global__ __launch_bounds__(256) void scan3(const int* __restrict__ excl,
                                             const int* __restrict__ partials,
                                             int n, int* __restrict__ rowptr) {
  const int i = blockIdx.x * 256 + threadIdx.x;
  if (i < n) rowptr[i] = excl[i] + partials[i >> 10];
}

// fill: atomic bump rowptr itself; afterwards rowptr[d] == end(d)
__global__ __launch_bounds__(256) void fill_csr2(const int* __restrict__ ei0,
                                                 const int* __restrict__ ei1,
                                                 int* __restrict__ rowptr,
                                                 int* __restrict__ csr_src) {
  const int e = blockIdx.x * 256 + threadIdx.x;
  if (e >= 2 * EE) return;
  int s, d;
  if (e < EE) { s = ei0[e]; d = ei0[EE + e]; }
  else        { s = ei1[e - EE]; d = NN + ei1[e]; }
  const int p = atomicAdd(&rowptr[d], 1);
  csr_src[p] = s;
}

// ---- per-destination attention, 4 edges in flight per wave (16-lane groups).
// 32-bit byte offsets for K/V gathers (one shift per edge serves both).
__global__ __launch_bounds__(256) void dst_attention(
    const unsigned short* __restrict__ Hq0, const unsigned short* __restrict__ K0,
    const unsigned short* __restrict__ V0, unsigned short* __restrict__ agg0,
    const unsigned short* __restrict__ Hq1, const unsigned short* __restrict__ K1,
    const unsigned short* __restrict__ V1, unsigned short* __restrict__ agg1,
    const int* __restrict__ rowptr, const int* __restrict__ deg,
    const int* __restrict__ csr_src) {
  const int gw = blockIdx.x * 4 + (threadIdx.x >> 6);
  if (gw >= 2 * NN) return;
  const bool rel1 = gw >= NN;
  const int node = rel1 ? gw - NN : gw;
  const unsigned short* Hq = rel1 ? Hq1 : Hq0;
  const char* Kb = (const char*)(rel1 ? K1 : K0);
  const char* Vb = (const char*)(rel1 ? V1 : V0);
  unsigned short* agg = rel1 ? agg1 : agg0;

  const int lane = threadIdx.x & 63;
  const int sub = lane & 15;   // dims [sub*8, sub*8+8)
  const int grp = lane >> 4;   // edge group 0..3
  const unsigned lboff = (unsigned)sub << 4;   // lane byte offset within row
  const int end = rowptr[gw];
  const int beg = end - deg[gw];
  const uint4 qu = *(const uint4*)(Hq + (size_t)node * DD + sub * 8);
#if defined(HAVE_FDOT2)
  const bf16x2t q0 = __builtin_bit_cast(bf16x2t, qu.x);
  const bf16x2t q1 = __builtin_bit_cast(bf16x2t, qu.y);
  const bf16x2t q2 = __builtin_bit_cast(bf16x2t, qu.z);
  const bf16x2t q3 = __builtin_bit_cast(bf16x2t, qu.w);
#else
  float qf[8];
  qf[0] = bf2f((unsigned short)qu.x); qf[1] = bf2f((unsigned short)(qu.x >> 16));
  qf[2] = bf2f((unsigned short)qu.y); qf[3] = bf2f((unsigned short)(qu.y >> 16));
  qf[4] = bf2f((unsigned short)qu.z); qf[5] = bf2f((unsigned short)(qu.z >> 16));
  qf[6] = bf2f((unsigned short)qu.w); qf[7] = bf2f((unsigned short)(qu.w >> 16));
#endif
  float av[8] = {0.f, 0.f, 0.f, 0.f, 0.f, 0.f, 0.f, 0.f};
  float lsum = 0.0f;
  for (int i = beg + grp; i < end; i += 4) {
    const unsigned roff = ((unsigned)csr_src[i] << 8) + lboff;
    const uint4 kp = *(const uint4*)(Kb + roff);
#if defined(HAVE_FDOT2)
    float p = __builtin_amdgcn_fdot2_f32_bf16(__builtin_bit_cast(bf16x2t, kp.x), q0, 0.0f, false);
    p = __builtin_amdgcn_fdot2_f32_bf16(__builtin_bit_cast(bf16x2t, kp.y), q1, p, false);
    p = __builtin_amdgcn_fdot2_f32_bf16(__builtin_bit_cast(bf16x2t, kp.z), q2, p, false);
    p = __builtin_amdgcn_fdot2_f32_bf16(__builtin_bit_cast(bf16x2t, kp.w), q3, p, false);
#else
    float p;
    p  = qf[0] * bf2f((unsigned short)kp.x) + qf[1] * bf2f((unsigned short)(kp.x >> 16));
    p += qf[2] * bf2f((unsigned short)kp.y) + qf[3] * bf2f((unsigned short)(kp.y >> 16));
    p += qf[4] * bf2f((unsigned short)kp.z) + qf[5] * bf2f((unsigned short)(kp.z >> 16));
    p += qf[6] * bf2f((unsigned short)kp.w) + qf[7] * bf2f((unsigned short)(kp.w >> 16));
#endif
    p += __shfl_xor(p, 1);
    p += __shfl_xor(p, 2);
    const float wgt = __expf(p * 0.17677669529663689f);  // 1/sqrt(32)
    const uint4 vp = *(const uint4*)(Vb + roff);
    lsum += wgt;
    av[0] += wgt * __uint_as_float(vp.x << 16);
    av[1] += wgt * __uint_as_float(vp.x & 0xFFFF0000u);
    av[2] += wgt * __uint_as_float(vp.y << 16);
    av[3] += wgt * __uint_as_float(vp.y & 0xFFFF0000u);
    av[4] += wgt * __uint_as_float(vp.z << 16);
    av[5] += wgt * __uint_as_float(vp.z & 0xFFFF0000u);
    av[6] += wgt * __uint_as_float(vp.w << 16);
    av[7] += wgt * __uint_as_float(vp.w & 0xFFFF0000u);
  }
#pragma unroll
  for (int d = 0; d < 8; ++d) {
    av[d] += __shfl_xor(av[d], 16);
    av[d] += __shfl_xor(av[d], 32);
  }
  lsum += __shfl_xor(lsum, 16);
  lsum += __shfl_xor(lsum, 32);
  if (grp == 0) {
    const float invl = (lsum > 0.0f) ? (1.0f / lsum) : 0.0f;
    uint4 o;
    o.x = (unsigned)f2bf(av[0] * invl) | ((unsigned)f2bf(av[1] * invl) << 16);
    o.y = (unsigned)f2bf(av[2] * invl) | ((unsigned)f2bf(av[3] * invl) << 16);
    o.z = (unsigned)f2bf(av[4] * invl) | ((unsigned)f2bf(av[5] * invl) << 16);
    o.w = (unsigned)f2bf(av[6] * invl) | ((unsigned)f2bf(av[7] * invl) << 16);
    *(uint4*)(agg + (size_t)node * DD + sub * 8) = o;
  }
}

extern "C" void kernel_launch(void* const* d_in, const int* in_sizes, int n_in,
                              void* d_out, int out_size, void* d_ws, size_t ws_size,
                              hipStream_t stream) {
  const float* x_drug  = (const float*)d_in[0];
  const float* x_dis   = (const float*)d_in[1];
  const float* Wp_drug = (const float*)d_in[2];
  const float* bp_drug = (const float*)d_in[3];
  const float* Wp_dis  = (const float*)d_in[4];
  const float* bp_dis  = (const float*)d_in[5];
  const float* Wk_r0   = (const float*)d_in[6];
  const float* Wv_r0   = (const float*)d_in[7];
  const float* Wk_r1   = (const float*)d_in[8];
  const float* Wv_r1   = (const float*)d_in[9];
  const float* Wu_drug = (const float*)d_in[10];
  const float* bu_drug = (const float*)d_in[11];
  const float* Wu_dis  = (const float*)d_in[12];
  const float* bu_dis  = (const float*)d_in[13];
  const float* g_drug  = (const float*)d_in[14];
  const float* be_drug = (const float*)d_in[15];
  const float* g_dis   = (const float*)d_in[16];
  const float* be_dis  = (const float*)d_in[17];
  const int* ei_r0     = (const int*)d_in[18];
  const int* ei_r1     = (const int*)d_in[19];

  float* out = (float*)d_out;
  float* out_drug = out;
  float* out_dis  = out + (size_t)NN * DD;

  const size_t ND = (size_t)NN * DD;
  char* w = (char*)d_ws;
  unsigned short* Kr0  = (unsigned short*)w; w += ND * 2;
  unsigned short* Vr0  = (unsigned short*)w; w += ND * 2;
  unsigned short* Kr1  = (unsigned short*)w; w += ND * 2;
  unsigned short* Vr1  = (unsigned short*)w; w += ND * 2;
  unsigned short* agdr = (unsigned short*)w; w += ND * 2;
  unsigned short* agdi = (unsigned short*)w; w += ND * 2;
  unsigned short* hb_dr = (unsigned short*)w; w += ND * 2;
  unsigned short* hb_di = (unsigned short*)w; w += ND * 2;
  unsigned short* Wpt_dr = (unsigned short*)w; w += DD * DD * 2;
  unsigned short* Wpt_di = (unsigned short*)w; w += DD * DD * 2;
  unsigned short* Wut_dr = (unsigned short*)w; w += DD * DD * 2;
  unsigned short* Wut_di = (unsigned short*)w; w += DD * DD * 2;
  unsigned short* Wkt0 = (unsigned short*)w; w += DD * DD * 2;
  unsigned short* Wvt0 = (unsigned short*)w; w += DD * DD * 2;
  unsigned short* Wkt1 = (unsigned short*)w; w += DD * DD * 2;
  unsigned short* Wvt1 = (unsigned short*)w; w += DD * DD * 2;
  float* bk0 = (float*)w; w += DD * 4;
  float* bv0 = (float*)w; w += DD * 4;
  float* bk1 = (float*)w; w += DD * 4;
  float* bv1 = (float*)w; w += DD * 4;
  int* deg      = (int*)w; w += 2 * NN * 4;
  int* excl     = (int*)w; w += 2 * NN * 4;
  int* rowptr   = (int*)w; w += (2 * NN + 1) * 4;
  int* partials = (int*)w; w += 256 * 4;
  int* csr_src  = (int*)w; w += 2 * EE * 4;

  const int gemm_blocks = (NN + 63) / 64;            // 1563
  const int cnt_blocks = (2 * EE + 255) / 256;       // 3125 (fill)
  const int nchunks = (2 * NN + 1023) / 1024;        // 196
  const int n256 = (2 * NN + 255) / 256;             // 782
  const int attn_blocks = (2 * NN + 3) / 4;          // 50000
  const int zero_blocks = (2 * NN + 255) / 256;      // 782
  dim3 b256(256), b512(512);

  // weight prep + deg zeroing in one launch
  prep_weights<<<514 + zero_blocks, b256, 0, stream>>>(
      Wp_drug, bp_drug, Wp_dis, bp_dis, Wu_drug, Wu_dis,
      Wk_r0, Wv_r0, Wk_r1, Wv_r1,
      Wpt_dr, Wpt_di, Wut_dr, Wut_di,
      Wkt0, bk0, Wvt0, bv0, Wkt1, bk1, Wvt1, bv1, deg);

  // persistent projections (1 block/CU, 512 thr) with degree-count tail
  fused_proj<<<PB, b512, 0, stream>>>(
      x_drug, Wpt_dr, bp_drug, Wkt0, bk0, Wvt0, bv0, hb_dr, Kr0, Vr0,
      x_dis,  Wpt_di, bp_dis,  Wkt1, bk1, Wvt1, bv1, hb_di, Kr1, Vr1,
      ei_r0, ei_r1, deg);

  scan1<<<nchunks, b256, 0, stream>>>(deg, excl, partials, 2 * NN);
  scan2<<<1, b256, 0, stream>>>(partials, nchunks);
  scan3<<<n256, b256, 0, stream>>>(excl, partials, 2 * NN, rowptr);
  fill_csr2<<<cnt_blocks, b256, 0, stream>>>(ei_r0, ei_r1, rowptr, csr_src);

  dst_attention<<<attn_blocks, b256, 0, stream>>>(
      hb_di, Kr0, Vr0, agdi,          // rel0: dst = dis
      hb_dr, Kr1, Vr1, agdr,          // rel1: dst = drug
      rowptr, deg, csr_src);

  update_ln2<<<2 * gemm_blocks, b256, 0, stream>>>(
      hb_dr, agdr, Wut_dr, bu_drug, g_drug, be_drug, out_drug,
      hb_di, agdi, Wut_di, bu_dis,  g_dis,  be_dis,  out_dis,
      gemm_blocks);
}

// Round 17
// 280.364 us; speedup vs baseline: 2.5475x; 1.7887x over previous
//
#include <hip/hip_runtime.h>
#include <math.h>

#define NN 100000
#define EE 400000
#define DD 128

typedef __attribute__((ext_vector_type(8))) short bf16x8;
typedef __attribute__((ext_vector_type(4))) float f32x4;

#if defined(__has_builtin)
#if __has_builtin(__builtin_amdgcn_fdot2_f32_bf16)
#define HAVE_FDOT2 1
typedef __attribute__((ext_vector_type(2))) __bf16 bf16x2t;
#endif
#endif

__device__ __forceinline__ unsigned short f2bf(float f) {
  unsigned u = __float_as_uint(f);
  u += 0x7FFF + ((u >> 16) & 1);   // round-to-nearest-even
  return (unsigned short)(u >> 16);
}
__device__ __forceinline__ float bf2f(unsigned short u) {
  return __uint_as_float(((unsigned)u) << 16);
}

// ---- one-shot weight prep (+ deg zeroing appended as extra blocks)
__global__ __launch_bounds__(256) void prep_weights(
    const float* __restrict__ Wp_dr, const float* __restrict__ bp_dr,
    const float* __restrict__ Wp_di, const float* __restrict__ bp_di,
    const float* __restrict__ Wu_dr, const float* __restrict__ Wu_di,
    const float* __restrict__ Bk0, const float* __restrict__ Bv0,
    const float* __restrict__ Bk1, const float* __restrict__ Bv1,
    unsigned short* __restrict__ Wpt_dr, unsigned short* __restrict__ Wpt_di,
    unsigned short* __restrict__ Wut_dr, unsigned short* __restrict__ Wut_di,
    unsigned short* __restrict__ Wkt0, float* __restrict__ bk0,
    unsigned short* __restrict__ Wvt0, float* __restrict__ bv0,
    unsigned short* __restrict__ Wkt1, float* __restrict__ bk1,
    unsigned short* __restrict__ Wvt1, float* __restrict__ bv1,
    int* __restrict__ deg) {
  const int b = blockIdx.x, t = threadIdx.x;
  if (b < 256) {
    const int id = b * 256 + t;
    const int m = id >> 14, rem = id & 16383, k = rem & 127, c = rem >> 7;
    const float* W = (m == 0) ? Wp_dr : (m == 1) ? Wp_di : (m == 2) ? Wu_dr : Wu_di;
    unsigned short* O = (m == 0) ? Wpt_dr : (m == 1) ? Wpt_di : (m == 2) ? Wut_dr : Wut_di;
    O[c * DD + k] = f2bf(W[(size_t)k * DD + c]);
  } else if (b < 512) {
    const int id = (b - 256) * 256 + t;
    const int m = id >> 14, rem = id & 16383, k = rem & 127, c = rem >> 7;
    const float* A = (m < 2) ? Wp_dr : Wp_di;
    const float* B = (m == 0) ? Bk0 : (m == 1) ? Bv0 : (m == 2) ? Bk1 : Bv1;
    unsigned short* O = (m == 0) ? Wkt0 : (m == 1) ? Wvt0 : (m == 2) ? Wkt1 : Wvt1;
    const float4* a4 = (const float4*)(A + (size_t)k * DD);
    float s = 0.0f;
#pragma unroll 8
    for (int j4 = 0; j4 < 32; ++j4) {
      const float4 av = a4[j4];
      s += av.x * B[(4 * j4 + 0) * DD + c] + av.y * B[(4 * j4 + 1) * DD + c]
         + av.z * B[(4 * j4 + 2) * DD + c] + av.w * B[(4 * j4 + 3) * DD + c];
    }
    O[c * DD + k] = f2bf(s);
  } else if (b < 514) {
    const int id = (b - 512) * 256 + t;
    if (id < 512) {
      const int m = id >> 7, c = id & 127;
      const float* bp = (m < 2) ? bp_dr : bp_di;
      const float* B = (m == 0) ? Bk0 : (m == 1) ? Bv0 : (m == 2) ? Bk1 : Bv1;
      float* bo = (m == 0) ? bk0 : (m == 1) ? bv0 : (m == 2) ? bk1 : bv1;
      float s = 0.0f;
#pragma unroll 8
      for (int j = 0; j < DD; ++j) s += bp[j] * B[j * DD + c];
      bo[c] = s;
    }
  } else {
    const int id = (b - 514) * 256 + t;
    if (id < 2 * NN) deg[id] = 0;
  }
}

// stage one transposed-bf16 weight (32KB) into LDS; full 4-bit slot swizzle
#define STAGE_W(SRC)                                                          \
  do {                                                                        \
    __syncthreads();                                                          \
    _Pragma("unroll") for (int i_ = threadIdx.x; i_ < 2048; i_ += 256) {      \
      const int L_ = i_ * 16;                                                 \
      *(float4*)((char*)WL + (L_ ^ (((L_ >> 8) & 15) << 4))) =                \
          ((const float4*)(SRC))[i_];                                         \
    }                                                                         \
    __syncthreads();                                                          \
  } while (0)

// one wave computes 16 rows x 128 cols: D = A(16x128) @ Wt^T via 8x4 mfma; bf16 out
__device__ __forceinline__ void mfma_tile_store(
    const unsigned short* WL, const bf16x8* a, int lane, int rowbase,
    bool wvalid, const float* __restrict__ bias,
    unsigned short* __restrict__ outb) {
  const int r0 = rowbase + (lane >> 4) * 4;
#pragma unroll
  for (int ni = 0; ni < 8; ++ni) {
    const int cl = ni * 16 + (lane & 15);
    f32x4 acc = {0.f, 0.f, 0.f, 0.f};
#pragma unroll
    for (int kk = 0; kk < 4; ++kk) {
      const int boff = cl * 256 + ((kk * 64 + (lane >> 4) * 16) ^ ((cl & 15) << 4));
      const bf16x8 bb = *(const bf16x8*)((const char*)WL + boff);
      acc = __builtin_amdgcn_mfma_f32_16x16x32_bf16(a[kk], bb, acc, 0, 0, 0);
    }
    if (wvalid) {
      const float bv = bias[cl];
#pragma unroll
      for (int r = 0; r < 4; ++r)
        outb[(size_t)(r0 + r) * DD + cl] = f2bf(acc[r] + bv);
    }
  }
}

// ---- fused proj (both types), R8 structure: 64 rows/block, 1 rowset/wave,
// + inline count_deg prefix blocks
__global__ __launch_bounds__(256) void fused_proj(
    const float* __restrict__ x0, const unsigned short* __restrict__ Wpt0,
    const float* __restrict__ bp0, const unsigned short* __restrict__ Wkta,
    const float* __restrict__ bka, const unsigned short* __restrict__ Wvta,
    const float* __restrict__ bva, unsigned short* __restrict__ h0,
    unsigned short* __restrict__ K0, unsigned short* __restrict__ V0,
    const float* __restrict__ x1, const unsigned short* __restrict__ Wpt1,
    const float* __restrict__ bp1, const unsigned short* __restrict__ Wktb,
    const float* __restrict__ bkb, const unsigned short* __restrict__ Wvtb,
    const float* __restrict__ bvb, unsigned short* __restrict__ h1,
    unsigned short* __restrict__ K1, unsigned short* __restrict__ V1,
    int half, int cntblocks,
    const int* __restrict__ ei0, const int* __restrict__ ei1,
    int* __restrict__ deg) {
  __shared__ unsigned short WL[DD * DD];
  int bid = blockIdx.x;
  if (bid < cntblocks) {  // degree count (independent prefix work)
    const int e = bid * 256 + threadIdx.x;
    if (e < 2 * EE) {
      const int d = (e < EE) ? ei0[EE + e] : (NN + ei1[e]);
      atomicAdd(&deg[d], 1);
    }
    return;
  }
  bid -= cntblocks;
  const bool second = bid >= half;
  if (second) bid -= half;
  const float* x = second ? x1 : x0;
  const unsigned short* Wpt = second ? Wpt1 : Wpt0;
  const float* bpv = second ? bp1 : bp0;
  const unsigned short* Wkt = second ? Wktb : Wkta;
  const float* bkv = second ? bkb : bka;
  const unsigned short* Wvt = second ? Wvtb : Wvta;
  const float* bvv = second ? bvb : bva;
  unsigned short* h = second ? h1 : h0;
  unsigned short* K = second ? K1 : K0;
  unsigned short* V = second ? V1 : V0;

  const int tid = threadIdx.x, lane = tid & 63, wid = tid >> 6;
  const int rowbase = bid * 64 + wid * 16;
  const bool wvalid = rowbase < NN;
  bf16x8 a[4];
  if (wvalid) {
    const int arow = rowbase + (lane & 15);
    const float* xr = x + (size_t)arow * DD + (lane >> 4) * 8;
#pragma unroll
    for (int kk = 0; kk < 4; ++kk) {
      const float4 f0 = *(const float4*)(xr + kk * 32);
      const float4 f1 = *(const float4*)(xr + kk * 32 + 4);
      a[kk][0] = (short)f2bf(f0.x); a[kk][1] = (short)f2bf(f0.y);
      a[kk][2] = (short)f2bf(f0.z); a[kk][3] = (short)f2bf(f0.w);
      a[kk][4] = (short)f2bf(f1.x); a[kk][5] = (short)f2bf(f1.y);
      a[kk][6] = (short)f2bf(f1.z); a[kk][7] = (short)f2bf(f1.w);
    }
  } else {
#pragma unroll
    for (int kk = 0; kk < 4; ++kk)
#pragma unroll
      for (int j = 0; j < 8; ++j) a[kk][j] = 0;
  }
  STAGE_W(Wpt);
  mfma_tile_store(WL, a, lane, rowbase, wvalid, bpv, h);
  STAGE_W(Wkt);
  mfma_tile_store(WL, a, lane, rowbase, wvalid, bkv, K);
  STAGE_W(Wvt);
  mfma_tile_store(WL, a, lane, rowbase, wvalid, bvv, V);
}

// ---- fused update GEMM + skip + LayerNorm + ReLU, R8 structure (1 rowset/wave)
__global__ __launch_bounds__(256) void update_ln2(
    const unsigned short* __restrict__ hA, const unsigned short* __restrict__ aggA,
    const unsigned short* __restrict__ WutA, const float* __restrict__ buA,
    const float* __restrict__ gA, const float* __restrict__ beA,
    float* __restrict__ outA,
    const unsigned short* __restrict__ hB, const unsigned short* __restrict__ aggB,
    const unsigned short* __restrict__ WutB, const float* __restrict__ buB,
    const float* __restrict__ gB, const float* __restrict__ beB,
    float* __restrict__ outB, int half) {
  __shared__ unsigned short WL[DD * DD];
  int bid = blockIdx.x;
  const bool second = bid >= half;
  if (second) bid -= half;
  const unsigned short* h = second ? hB : hA;
  const unsigned short* agg = second ? aggB : aggA;
  const unsigned short* Wut = second ? WutB : WutA;
  const float* bu = second ? buB : buA;
  const float* g = second ? gB : gA;
  const float* be = second ? beB : beA;
  float* out = second ? outB : outA;

  const int tid = threadIdx.x, lane = tid & 63, wid = tid >> 6;
  const int rowbase = bid * 64 + wid * 16;
  const bool wvalid = rowbase < NN;
  bf16x8 a[4];
  if (wvalid) {
    const int arow = rowbase + (lane & 15);
#pragma unroll
    for (int kk = 0; kk < 4; ++kk)
      a[kk] = *(const bf16x8*)(agg + (size_t)arow * DD + kk * 32 + (lane >> 4) * 8);
  } else {
#pragma unroll
    for (int kk = 0; kk < 4; ++kk)
#pragma unroll
      for (int j = 0; j < 8; ++j) a[kk][j] = 0;
  }
#pragma unroll
  for (int i_ = tid; i_ < 2048; i_ += 256) {
    const int L_ = i_ * 16;
    *(float4*)((char*)WL + (L_ ^ (((L_ >> 8) & 15) << 4))) =
        ((const float4*)Wut)[i_];
  }
  __syncthreads();
  f32x4 acc[8];
  const int r0 = rowbase + (lane >> 4) * 4;
#pragma unroll
  for (int ni = 0; ni < 8; ++ni) {
    const int cl = ni * 16 + (lane & 15);
    acc[ni] = (f32x4){0.f, 0.f, 0.f, 0.f};
#pragma unroll
    for (int kk = 0; kk < 4; ++kk) {
      const int boff = cl * 256 + ((kk * 64 + (lane >> 4) * 16) ^ ((cl & 15) << 4));
      const bf16x8 bb = *(const bf16x8*)((const char*)WL + boff);
      acc[ni] = __builtin_amdgcn_mfma_f32_16x16x32_bf16(a[kk], bb, acc[ni], 0, 0, 0);
    }
  }
  if (!wvalid) return;
  // x = h + agg@Wu + bu
#pragma unroll
  for (int ni = 0; ni < 8; ++ni) {
    const int cl = ni * 16 + (lane & 15);
    const float bv = bu[cl];
#pragma unroll
    for (int r = 0; r < 4; ++r)
      acc[ni][r] += bf2f(h[(size_t)(r0 + r) * DD + cl]) + bv;
  }
  // LayerNorm stats: reduce over 8 in-lane cols x 16 lanes (lanes share rows)
  float mean[4], inv[4];
#pragma unroll
  for (int r = 0; r < 4; ++r) {
    float s = 0.f, q = 0.f;
#pragma unroll
    for (int ni = 0; ni < 8; ++ni) {
      const float v = acc[ni][r];
      s += v; q += v * v;
    }
    s += __shfl_xor(s, 1); q += __shfl_xor(q, 1);
    s += __shfl_xor(s, 2); q += __shfl_xor(q, 2);
    s += __shfl_xor(s, 4); q += __shfl_xor(q, 4);
    s += __shfl_xor(s, 8); q += __shfl_xor(q, 8);
    const float mu = s * (1.0f / 128.0f);
    mean[r] = mu;
    inv[r] = rsqrtf(q * (1.0f / 128.0f) - mu * mu + 1e-5f);
  }
#pragma unroll
  for (int ni = 0; ni < 8; ++ni) {
    const int cl = ni * 16 + (lane & 15);
    const float gv = g[cl], bev = be[cl];
#pragma unroll
    for (int r = 0; r < 4; ++r)
      out[(size_t)(r0 + r) * DD + cl] =
          fmaxf((acc[ni][r] - mean[r]) * inv[r] * gv + bev, 0.0f);
  }
}

// ---------------- CSR scan chain (deg counted inside fused_proj launch)
__global__ __launch_bounds__(256) void scan1(const int* __restrict__ deg,
                                             int* __restrict__ excl,
                                             int* __restrict__ partials, int n) {
  __shared__ int ls[256];
  const int b0 = blockIdx.x * 1024;
  const int t = threadIdx.x;
  int v[4];
  int s = 0;
#pragma unroll
  for (int i = 0; i < 4; ++i) {
    const int idx = b0 + t * 4 + i;
    v[i] = (idx < n) ? deg[idx] : 0;
    s += v[i];
  }
  ls[t] = s;
  __syncthreads();
  for (int off = 1; off < 256; off <<= 1) {
    const int x = (t >= off) ? ls[t - off] : 0;
    __syncthreads();
    ls[t] += x;
    __syncthreads();
  }
  int ex = ls[t] - s;
#pragma unroll
  for (int i = 0; i < 4; ++i) {
    const int idx = b0 + t * 4 + i;
    if (idx < n) excl[idx] = ex;
    ex += v[i];
  }
  if (t == 255) partials[blockIdx.x] = ls[255];
}

__global__ __launch_bounds__(256) void scan2(int* __restrict__ partials, int nb) {
  __shared__ int ls[256];
  const int t = threadIdx.x;
  const int v = (t < nb) ? partials[t] : 0;
  ls[t] = v;
  __syncthreads();
  for (int off = 1; off < 256; off <<= 1) {
    const int x = (t >= off) ? ls[t - off] : 0;
    __syncthreads();
    ls[t] += x;
    __syncthreads();
  }
  if (t < nb) partials[t] = ls[t] - v;
}

__global__ __launch_bounds__(256) void scan3(const int* __restrict__ excl,
                                             const int* __restrict__ partials,
                                             int n, int* __restrict__ rowptr) {
  const int i = blockIdx.x * 256 + threadIdx.x;
  if (i < n) rowptr[i] = excl[i] + partials[i >> 10];
}

// fill: atomic bump rowptr itself; afterwards rowptr[d] == end(d)
__global__ __launch_bounds__(256) void fill_csr2(const int* __restrict__ ei0,
                                                 const int* __restrict__ ei1,
                                                 int* __restrict__ rowptr,
                                                 int* __restrict__ csr_src) {
  const int e = blockIdx.x * 256 + threadIdx.x;
  if (e >= 2 * EE) return;
  int s, d;
  if (e < EE) { s = ei0[e]; d = ei0[EE + e]; }
  else        { s = ei1[e - EE]; d = NN + ei1[e]; }
  const int p = atomicAdd(&rowptr[d], 1);
  csr_src[p] = s;
}

// ---- per-destination attention, 4 edges in flight per wave (16-lane groups).
// 32-bit byte offsets for K/V gathers (one shift per edge serves both).
__global__ __launch_bounds__(256) void dst_attention(
    const unsigned short* __restrict__ Hq0, const unsigned short* __restrict__ K0,
    const unsigned short* __restrict__ V0, unsigned short* __restrict__ agg0,
    const unsigned short* __restrict__ Hq1, const unsigned short* __restrict__ K1,
    const unsigned short* __restrict__ V1, unsigned short* __restrict__ agg1,
    const int* __restrict__ rowptr, const int* __restrict__ deg,
    const int* __restrict__ csr_src) {
  const int gw = blockIdx.x * 4 + (threadIdx.x >> 6);
  if (gw >= 2 * NN) return;
  const bool rel1 = gw >= NN;
  const int node = rel1 ? gw - NN : gw;
  const unsigned short* Hq = rel1 ? Hq1 : Hq0;
  const char* Kb = (const char*)(rel1 ? K1 : K0);
  const char* Vb = (const char*)(rel1 ? V1 : V0);
  unsigned short* agg = rel1 ? agg1 : agg0;

  const int lane = threadIdx.x & 63;
  const int sub = lane & 15;   // dims [sub*8, sub*8+8)
  const int grp = lane >> 4;   // edge group 0..3
  const unsigned lboff = (unsigned)sub << 4;   // lane byte offset within row
  const int end = rowptr[gw];
  const int beg = end - deg[gw];
  const uint4 qu = *(const uint4*)(Hq + (size_t)node * DD + sub * 8);
#if defined(HAVE_FDOT2)
  const bf16x2t q0 = __builtin_bit_cast(bf16x2t, qu.x);
  const bf16x2t q1 = __builtin_bit_cast(bf16x2t, qu.y);
  const bf16x2t q2 = __builtin_bit_cast(bf16x2t, qu.z);
  const bf16x2t q3 = __builtin_bit_cast(bf16x2t, qu.w);
#else
  float qf[8];
  qf[0] = bf2f((unsigned short)qu.x); qf[1] = bf2f((unsigned short)(qu.x >> 16));
  qf[2] = bf2f((unsigned short)qu.y); qf[3] = bf2f((unsigned short)(qu.y >> 16));
  qf[4] = bf2f((unsigned short)qu.z); qf[5] = bf2f((unsigned short)(qu.z >> 16));
  qf[6] = bf2f((unsigned short)qu.w); qf[7] = bf2f((unsigned short)(qu.w >> 16));
#endif
  float av[8] = {0.f, 0.f, 0.f, 0.f, 0.f, 0.f, 0.f, 0.f};
  float lsum = 0.0f;
  for (int i = beg + grp; i < end; i += 4) {
    const unsigned roff = ((unsigned)csr_src[i] << 8) + lboff;
    const uint4 kp = *(const uint4*)(Kb + roff);
#if defined(HAVE_FDOT2)
    float p = __builtin_amdgcn_fdot2_f32_bf16(__builtin_bit_cast(bf16x2t, kp.x), q0, 0.0f, false);
    p = __builtin_amdgcn_fdot2_f32_bf16(__builtin_bit_cast(bf16x2t, kp.y), q1, p, false);
    p = __builtin_amdgcn_fdot2_f32_bf16(__builtin_bit_cast(bf16x2t, kp.z), q2, p, false);
    p = __builtin_amdgcn_fdot2_f32_bf16(__builtin_bit_cast(bf16x2t, kp.w), q3, p, false);
#else
    float p;
    p  = qf[0] * bf2f((unsigned short)kp.x) + qf[1] * bf2f((unsigned short)(kp.x >> 16));
    p += qf[2] * bf2f((unsigned short)kp.y) + qf[3] * bf2f((unsigned short)(kp.y >> 16));
    p += qf[4] * bf2f((unsigned short)kp.z) + qf[5] * bf2f((unsigned short)(kp.z >> 16));
    p += qf[6] * bf2f((unsigned short)kp.w) + qf[7] * bf2f((unsigned short)(kp.w >> 16));
#endif
    p += __shfl_xor(p, 1);
    p += __shfl_xor(p, 2);
    const float wgt = __expf(p * 0.17677669529663689f);  // 1/sqrt(32)
    const uint4 vp = *(const uint4*)(Vb + roff);
    lsum += wgt;
    av[0] += wgt * __uint_as_float(vp.x << 16);
    av[1] += wgt * __uint_as_float(vp.x & 0xFFFF0000u);
    av[2] += wgt * __uint_as_float(vp.y << 16);
    av[3] += wgt * __uint_as_float(vp.y & 0xFFFF0000u);
    av[4] += wgt * __uint_as_float(vp.z << 16);
    av[5] += wgt * __uint_as_float(vp.z & 0xFFFF0000u);
    av[6] += wgt * __uint_as_float(vp.w << 16);
    av[7] += wgt * __uint_as_float(vp.w & 0xFFFF0000u);
  }
#pragma unroll
  for (int d = 0; d < 8; ++d) {
    av[d] += __shfl_xor(av[d], 16);
    av[d] += __shfl_xor(av[d], 32);
  }
  lsum += __shfl_xor(lsum, 16);
  lsum += __shfl_xor(lsum, 32);
  if (grp == 0) {
    const float invl = (lsum > 0.0f) ? (1.0f / lsum) : 0.0f;
    uint4 o;
    o.x = (unsigned)f2bf(av[0] * invl) | ((unsigned)f2bf(av[1] * invl) << 16);
    o.y = (unsigned)f2bf(av[2] * invl) | ((unsigned)f2bf(av[3] * invl) << 16);
    o.z = (unsigned)f2bf(av[4] * invl) | ((unsigned)f2bf(av[5] * invl) << 16);
    o.w = (unsigned)f2bf(av[6] * invl) | ((unsigned)f2bf(av[7] * invl) << 16);
    *(uint4*)(agg + (size_t)node * DD + sub * 8) = o;
  }
}

extern "C" void kernel_launch(void* const* d_in, const int* in_sizes, int n_in,
                              void* d_out, int out_size, void* d_ws, size_t ws_size,
                              hipStream_t stream) {
  const float* x_drug  = (const float*)d_in[0];
  const float* x_dis   = (const float*)d_in[1];
  const float* Wp_drug = (const float*)d_in[2];
  const float* bp_drug = (const float*)d_in[3];
  const float* Wp_dis  = (const float*)d_in[4];
  const float* bp_dis  = (const float*)d_in[5];
  const float* Wk_r0   = (const float*)d_in[6];
  const float* Wv_r0   = (const float*)d_in[7];
  const float* Wk_r1   = (const float*)d_in[8];
  const float* Wv_r1   = (const float*)d_in[9];
  const float* Wu_drug = (const float*)d_in[10];
  const float* bu_drug = (const float*)d_in[11];
  const float* Wu_dis  = (const float*)d_in[12];
  const float* bu_dis  = (const float*)d_in[13];
  const float* g_drug  = (const float*)d_in[14];
  const float* be_drug = (const float*)d_in[15];
  const float* g_dis   = (const float*)d_in[16];
  const float* be_dis  = (const float*)d_in[17];
  const int* ei_r0     = (const int*)d_in[18];
  const int* ei_r1     = (const int*)d_in[19];

  float* out = (float*)d_out;
  float* out_drug = out;
  float* out_dis  = out + (size_t)NN * DD;

  const size_t ND = (size_t)NN * DD;
  char* w = (char*)d_ws;
  unsigned short* Kr0  = (unsigned short*)w; w += ND * 2;
  unsigned short* Vr0  = (unsigned short*)w; w += ND * 2;
  unsigned short* Kr1  = (unsigned short*)w; w += ND * 2;
  unsigned short* Vr1  = (unsigned short*)w; w += ND * 2;
  unsigned short* agdr = (unsigned short*)w; w += ND * 2;
  unsigned short* agdi = (unsigned short*)w; w += ND * 2;
  unsigned short* hb_dr = (unsigned short*)w; w += ND * 2;
  unsigned short* hb_di = (unsigned short*)w; w += ND * 2;
  unsigned short* Wpt_dr = (unsigned short*)w; w += DD * DD * 2;
  unsigned short* Wpt_di = (unsigned short*)w; w += DD * DD * 2;
  unsigned short* Wut_dr = (unsigned short*)w; w += DD * DD * 2;
  unsigned short* Wut_di = (unsigned short*)w; w += DD * DD * 2;
  unsigned short* Wkt0 = (unsigned short*)w; w += DD * DD * 2;
  unsigned short* Wvt0 = (unsigned short*)w; w += DD * DD * 2;
  unsigned short* Wkt1 = (unsigned short*)w; w += DD * DD * 2;
  unsigned short* Wvt1 = (unsigned short*)w; w += DD * DD * 2;
  float* bk0 = (float*)w; w += DD * 4;
  float* bv0 = (float*)w; w += DD * 4;
  float* bk1 = (float*)w; w += DD * 4;
  float* bv1 = (float*)w; w += DD * 4;
  int* deg      = (int*)w; w += 2 * NN * 4;
  int* excl     = (int*)w; w += 2 * NN * 4;
  int* rowptr   = (int*)w; w += (2 * NN + 1) * 4;
  int* partials = (int*)w; w += 256 * 4;
  int* csr_src  = (int*)w; w += 2 * EE * 4;

  const int gemm_blocks = (NN + 63) / 64;            // 1563
  const int cnt_blocks = (2 * EE + 255) / 256;       // 3125
  const int nchunks = (2 * NN + 1023) / 1024;        // 196
  const int n256 = (2 * NN + 255) / 256;             // 782
  const int attn_blocks = (2 * NN + 3) / 4;          // 50000
  const int zero_blocks = (2 * NN + 255) / 256;      // 782
  dim3 b256(256);

  // weight prep + deg zeroing in one launch
  prep_weights<<<514 + zero_blocks, b256, 0, stream>>>(
      Wp_drug, bp_drug, Wp_dis, bp_dis, Wu_drug, Wu_dis,
      Wk_r0, Wv_r0, Wk_r1, Wv_r1,
      Wpt_dr, Wpt_di, Wut_dr, Wut_di,
      Wkt0, bk0, Wvt0, bv0, Wkt1, bk1, Wvt1, bv1, deg);

  // degree count (prefix blocks) || fused projections (both node types)
  fused_proj<<<cnt_blocks + 2 * gemm_blocks, b256, 0, stream>>>(
      x_drug, Wpt_dr, bp_drug, Wkt0, bk0, Wvt0, bv0, hb_dr, Kr0, Vr0,
      x_dis,  Wpt_di, bp_dis,  Wkt1, bk1, Wvt1, bv1, hb_di, Kr1, Vr1,
      gemm_blocks, cnt_blocks, ei_r0, ei_r1, deg);

  scan1<<<nchunks, b256, 0, stream>>>(deg, excl, partials, 2 * NN);
  scan2<<<1, b256, 0, stream>>>(partials, nchunks);
  scan3<<<n256, b256, 0, stream>>>(excl, partials, 2 * NN, rowptr);
  fill_csr2<<<cnt_blocks, b256, 0, stream>>>(ei_r0, ei_r1, rowptr, csr_src);

  dst_attention<<<attn_blocks, b256, 0, stream>>>(
      hb_di, Kr0, Vr0, agdi,          // rel0: dst = dis
      hb_dr, Kr1, Vr1, agdr,          // rel1: dst = drug
      rowptr, deg, csr_src);

  update_ln2<<<2 * gemm_blocks, b256, 0, stream>>>(
      hb_dr, agdr, Wut_dr, bu_drug, g_drug, be_drug, out_drug,
      hb_di, agdi, Wut_di, bu_dis,  g_dis,  be_dis,  out_dis,
      gemm_blocks);
}